// Round 3
// baseline (122.385 us; speedup 1.0000x reference)
//
#include <hip/hip_runtime.h>
#include <math.h>

#define B_      16
#define C_IN_   128
#define C_OUT_  3
#define W_DIM_  512
#define HW_     65536          // 256*256
#define CONV_CLAMP_ 256.0f

typedef float f32x4 __attribute__((ext_vector_type(4)));

// ---------------------------------------------------------------------------
// k_prep: fused styles + eff computation. One block per batch b.
//   s[j]   = dot(w[b], affine_w[j]) / sqrt(512) + affine_b[j]     (j = 0..383)
//   style  = (s[i]*s[i+128] + s[i+256]) / sqrt(128)
//   eff[b][i] = f32x4(style*weight[0][i], style*weight[1][i],
//                     style*weight[2][i], 0)
// ---------------------------------------------------------------------------
__global__ __launch_bounds__(256) void k_prep(
        const float* __restrict__ w,
        const float* __restrict__ affine_w,
        const float* __restrict__ affine_b,
        const float* __restrict__ weight,
        float* __restrict__ eff) {
    __shared__ f32x4 w_sh[W_DIM_ / 4];      // 128 f32x4 = w row
    __shared__ float s_sh[3 * C_IN_];       // 384 styles pre-split
    int b = blockIdx.x;

    if (threadIdx.x < W_DIM_ / 4)
        w_sh[threadIdx.x] =
            reinterpret_cast<const f32x4*>(w + (size_t)b * W_DIM_)[threadIdx.x];
    __syncthreads();

    int group = threadIdx.x >> 4;           // 16 groups of 16 lanes
    int lane  = threadIdx.x & 15;
    #pragma unroll
    for (int j0 = 0; j0 < 24; ++j0) {
        int j = group + j0 * 16;            // 16 groups * 24 iters = 384 rows
        const f32x4* arow =
            reinterpret_cast<const f32x4*>(affine_w + (size_t)j * W_DIM_);
        float p = 0.f;
        #pragma unroll
        for (int t = 0; t < 8; ++t) {
            f32x4 av = arow[lane + t * 16];
            f32x4 wv = w_sh[lane + t * 16];
            p = fmaf(av.x, wv.x, p);
            p = fmaf(av.y, wv.y, p);
            p = fmaf(av.z, wv.z, p);
            p = fmaf(av.w, wv.w, p);
        }
        #pragma unroll
        for (int off = 8; off; off >>= 1)
            p += __shfl_xor(p, off, 16);
        if (lane == 0)
            s_sh[j] = fmaf(p, 0.04419417382415922f /*1/sqrt(512)*/, affine_b[j]);
    }
    __syncthreads();

    if (threadIdx.x < C_IN_) {
        int i = threadIdx.x;
        float style = fmaf(s_sh[i], s_sh[i + C_IN_], s_sh[i + 2 * C_IN_])
                      * 0.08838834764831845f;   // 1/sqrt(128)
        f32x4 e;
        e.x = style * weight[0 * C_IN_ + i];
        e.y = style * weight[1 * C_IN_ + i];
        e.z = style * weight[2 * C_IN_ + i];
        e.w = 0.f;
        reinterpret_cast<f32x4*>(eff)[b * C_IN_ + i] = e;
    }
}

// ---------------------------------------------------------------------------
// k_main: the 512 MB streaming pass.
// 512 blocks (32 per batch). Block owns 2048 contiguous pixels, visited as
// two coalesced 1024-px segments -> 8 KB contiguous per channel row.
// Channel loop start rotated per block to decorrelate DRAM streams.
// Non-temporal loads/stores (zero reuse).
// ---------------------------------------------------------------------------
__global__ __launch_bounds__(256) void k_main(
        const float* __restrict__ x,
        const float* __restrict__ eff,
        const float* __restrict__ bias,
        float* __restrict__ out) {
    __shared__ f32x4 eff_lds[C_IN_];
    int b   = blockIdx.x >> 5;       // 32 blocks per batch
    int blk = blockIdx.x & 31;

    if (threadIdx.x < C_IN_)
        eff_lds[threadIdx.x] =
            reinterpret_cast<const f32x4*>(eff)[b * C_IN_ + threadIdx.x];
    __syncthreads();

    const int pix = blk * 2048 + threadIdx.x * 4;       // segment 0; seg1 = +1024
    const float* xb = x + (size_t)b * C_IN_ * HW_ + pix;

    f32x4 aA[C_OUT_], aB[C_OUT_];
    #pragma unroll
    for (int o = 0; o < C_OUT_; ++o) {
        aA[o] = (f32x4){0.f, 0.f, 0.f, 0.f};
        aB[o] = (f32x4){0.f, 0.f, 0.f, 0.f};
    }

    const int rot = (blk << 2) & 127;    // per-block channel-start rotation

    #pragma unroll 4
    for (int ii = 0; ii < C_IN_; ++ii) {
        int i = (ii + rot) & 127;
        const float* p = xb + ((size_t)i << 16);
        f32x4 x0 = __builtin_nontemporal_load(reinterpret_cast<const f32x4*>(p));
        f32x4 x1 = __builtin_nontemporal_load(reinterpret_cast<const f32x4*>(p + 1024));
        f32x4 e  = eff_lds[i];
        const float s[C_OUT_] = {e.x, e.y, e.z};
        #pragma unroll
        for (int o = 0; o < C_OUT_; ++o) {
            aA[o].x = fmaf(x0.x, s[o], aA[o].x);
            aA[o].y = fmaf(x0.y, s[o], aA[o].y);
            aA[o].z = fmaf(x0.z, s[o], aA[o].z);
            aA[o].w = fmaf(x0.w, s[o], aA[o].w);
            aB[o].x = fmaf(x1.x, s[o], aB[o].x);
            aB[o].y = fmaf(x1.y, s[o], aB[o].y);
            aB[o].z = fmaf(x1.z, s[o], aB[o].z);
            aB[o].w = fmaf(x1.w, s[o], aB[o].w);
        }
    }

    auto clip4 = [](f32x4 v, float bb) {
        f32x4 r;
        r.x = fminf(fmaxf(v.x + bb, -CONV_CLAMP_), CONV_CLAMP_);
        r.y = fminf(fmaxf(v.y + bb, -CONV_CLAMP_), CONV_CLAMP_);
        r.z = fminf(fmaxf(v.z + bb, -CONV_CLAMP_), CONV_CLAMP_);
        r.w = fminf(fmaxf(v.w + bb, -CONV_CLAMP_), CONV_CLAMP_);
        return r;
    };

    float* ob = out + (size_t)b * C_OUT_ * HW_ + pix;
    #pragma unroll
    for (int o = 0; o < C_OUT_; ++o) {
        float bb = bias[o];
        __builtin_nontemporal_store(clip4(aA[o], bb),
            reinterpret_cast<f32x4*>(ob + (size_t)o * HW_));
        __builtin_nontemporal_store(clip4(aB[o], bb),
            reinterpret_cast<f32x4*>(ob + (size_t)o * HW_ + 1024));
    }
}

// ---------------------------------------------------------------------------
extern "C" void kernel_launch(void* const* d_in, const int* in_sizes, int n_in,
                              void* d_out, int out_size, void* d_ws, size_t ws_size,
                              hipStream_t stream) {
    const float* x        = (const float*)d_in[0];
    const float* w        = (const float*)d_in[1];
    const float* weight   = (const float*)d_in[2];
    const float* bias     = (const float*)d_in[3];
    const float* affine_w = (const float*)d_in[4];
    const float* affine_b = (const float*)d_in[5];
    float* out = (float*)d_out;

    float* eff = (float*)d_ws;                      // 16*128 f32x4

    k_prep<<<B_,  256, 0, stream>>>(w, affine_w, affine_b, weight, eff);
    k_main<<<512, 256, 0, stream>>>(x, eff, bias, out);
}

// Round 4
// 102.504 us; speedup vs baseline: 1.1939x; 1.1939x over previous
//
#include <hip/hip_runtime.h>
#include <math.h>

#define B_      16
#define C_IN_   128
#define C_OUT_  3
#define W_DIM_  512
#define HW_     65536          // 256*256
#define CONV_CLAMP_ 256.0f

typedef float f32x4 __attribute__((ext_vector_type(4)));

// ---------------------------------------------------------------------------
// Kernel 1: s[b][j] = (w[b] . affine_w[j]) / sqrt(512) + affine_b[j]
// One 16-lane group per (b,j). 16*384 = 6144 groups -> 384 blocks * 256 thr.
// ---------------------------------------------------------------------------
__global__ __launch_bounds__(256) void k_styles(
        const float* __restrict__ w,
        const float* __restrict__ affine_w,
        const float* __restrict__ affine_b,
        float* __restrict__ s_out) {
    int gid   = blockIdx.x * blockDim.x + threadIdx.x;
    int group = gid >> 4;            // (b,j) pair
    int lane  = gid & 15;
    if (group >= B_ * 3 * C_IN_) return;
    int b = group / (3 * C_IN_);
    int j = group - b * (3 * C_IN_);
    const float* wrow = w        + (size_t)b * W_DIM_;
    const float* arow = affine_w + (size_t)j * W_DIM_;
    float p = 0.f;
    #pragma unroll
    for (int t = 0; t < W_DIM_ / 16; ++t) {
        int k = lane + t * 16;
        p = fmaf(wrow[k], arow[k], p);
    }
    #pragma unroll
    for (int off = 8; off >= 1; off >>= 1)
        p += __shfl_xor(p, off, 16);
    if (lane == 0) {
        const float fc_gain = 0.04419417382415922f;   // 1/sqrt(512)
        s_out[group] = fmaf(p, fc_gain, affine_b[j]);
    }
}

// ---------------------------------------------------------------------------
// Kernel 2: eff[b][i] = f32x4( style * weight[o][i] for o=0..2, 0 )
//           style = (m1*m2 + m3) / sqrt(128)
// ---------------------------------------------------------------------------
__global__ __launch_bounds__(256) void k_eff(
        const float* __restrict__ s,
        const float* __restrict__ weight,
        float* __restrict__ eff) {
    int gid = blockIdx.x * blockDim.x + threadIdx.x;   // (b,i)
    if (gid >= B_ * C_IN_) return;
    int b = gid / C_IN_;
    int i = gid - b * C_IN_;
    const float* sb = s + (size_t)b * 3 * C_IN_;
    float m1 = sb[i], m2 = sb[i + C_IN_], m3 = sb[i + 2 * C_IN_];
    float style = fmaf(m1, m2, m3) * 0.08838834764831845f;  // 1/sqrt(128)
    f32x4 e;
    e.x = style * weight[0 * C_IN_ + i];
    e.y = style * weight[1 * C_IN_ + i];
    e.z = style * weight[2 * C_IN_ + i];
    e.w = 0.f;
    reinterpret_cast<f32x4*>(eff)[gid] = e;
}

// ---------------------------------------------------------------------------
// Kernel 3 (the 512 MB pass) — identical structure to R1 (the 114 us control),
// single change: non-temporal loads/stores (x streamed once, > L3 capacity).
// 1024 blocks (64/batch), 256 thr, 4 px/thread, no channel rotation.
// ---------------------------------------------------------------------------
__global__ __launch_bounds__(256) void k_main(
        const float* __restrict__ x,
        const float* __restrict__ eff,
        const float* __restrict__ bias,
        float* __restrict__ out) {
    __shared__ f32x4 eff_lds[C_IN_];
    int b   = blockIdx.x >> 6;       // 64 blocks per batch
    int blk = blockIdx.x & 63;

    if (threadIdx.x < C_IN_)
        eff_lds[threadIdx.x] =
            reinterpret_cast<const f32x4*>(eff)[b * C_IN_ + threadIdx.x];
    __syncthreads();

    int pix = blk * 1024 + threadIdx.x * 4;     // 256 thr * 4 px = 1024 px
    const float* xb = x + (size_t)b * C_IN_ * HW_ + pix;

    f32x4 a0 = {0.f,0.f,0.f,0.f};
    f32x4 a1 = {0.f,0.f,0.f,0.f};
    f32x4 a2 = {0.f,0.f,0.f,0.f};

    #pragma unroll 8
    for (int i = 0; i < C_IN_; ++i) {
        f32x4 xv = __builtin_nontemporal_load(
            reinterpret_cast<const f32x4*>(xb + ((size_t)i << 16)));
        f32x4 e  = eff_lds[i];
        a0.x = fmaf(xv.x, e.x, a0.x);
        a0.y = fmaf(xv.y, e.x, a0.y);
        a0.z = fmaf(xv.z, e.x, a0.z);
        a0.w = fmaf(xv.w, e.x, a0.w);
        a1.x = fmaf(xv.x, e.y, a1.x);
        a1.y = fmaf(xv.y, e.y, a1.y);
        a1.z = fmaf(xv.z, e.y, a1.z);
        a1.w = fmaf(xv.w, e.y, a1.w);
        a2.x = fmaf(xv.x, e.z, a2.x);
        a2.y = fmaf(xv.y, e.z, a2.y);
        a2.z = fmaf(xv.z, e.z, a2.z);
        a2.w = fmaf(xv.w, e.z, a2.w);
    }

    float b0 = bias[0], b1 = bias[1], b2 = bias[2];
    auto clip4 = [](f32x4 v, float bb) {
        f32x4 r;
        r.x = fminf(fmaxf(v.x + bb, -CONV_CLAMP_), CONV_CLAMP_);
        r.y = fminf(fmaxf(v.y + bb, -CONV_CLAMP_), CONV_CLAMP_);
        r.z = fminf(fmaxf(v.z + bb, -CONV_CLAMP_), CONV_CLAMP_);
        r.w = fminf(fmaxf(v.w + bb, -CONV_CLAMP_), CONV_CLAMP_);
        return r;
    };

    float* ob = out + (size_t)b * C_OUT_ * HW_ + pix;
    __builtin_nontemporal_store(clip4(a0, b0), reinterpret_cast<f32x4*>(ob));
    __builtin_nontemporal_store(clip4(a1, b1), reinterpret_cast<f32x4*>(ob + HW_));
    __builtin_nontemporal_store(clip4(a2, b2), reinterpret_cast<f32x4*>(ob + 2 * HW_));
}

// ---------------------------------------------------------------------------
extern "C" void kernel_launch(void* const* d_in, const int* in_sizes, int n_in,
                              void* d_out, int out_size, void* d_ws, size_t ws_size,
                              hipStream_t stream) {
    const float* x        = (const float*)d_in[0];
    const float* w        = (const float*)d_in[1];
    const float* weight   = (const float*)d_in[2];
    const float* bias     = (const float*)d_in[3];
    const float* affine_w = (const float*)d_in[4];
    const float* affine_b = (const float*)d_in[5];
    float* out = (float*)d_out;

    float* s_ws  = (float*)d_ws;                    // 16*384 floats
    float* eff   = s_ws + B_ * 3 * C_IN_;           // 16*128 f32x4

    k_styles<<<384, 256, 0, stream>>>(w, affine_w, affine_b, s_ws);
    k_eff   <<<8,   256, 0, stream>>>(s_ws, weight, eff);
    k_main  <<<1024,256, 0, stream>>>(x, eff, bias, out);
}